// Round 1
// 825.099 us; speedup vs baseline: 1.0187x; 1.0187x over previous
//
#include <hip/hip_runtime.h>
#include <hip/hip_bf16.h>

#define N_NODESC 50000
#define N_EDGESC 1600000
#define SDIM 64
#define VDIM 32
#define HID 96
#define IN_DIMC 163
#define MPITCH 99   // f32 msg tile pitch: (99*4)%32 banks = 12 -> staggered stores

typedef float f32x4 __attribute__((ext_vector_type(4)));
typedef short s16x8 __attribute__((ext_vector_type(8)));
typedef short s16x4 __attribute__((ext_vector_type(4)));

__device__ __forceinline__ float bf2f(__hip_bfloat16 x) { return __bfloat162float(x); }
__device__ __forceinline__ __hip_bfloat16 f2bf(float x) { return __float2bfloat16(x); }
__device__ __forceinline__ float bfbits2f(short b) {
    unsigned u = ((unsigned)(unsigned short)b) << 16;
    return __builtin_bit_cast(float, u);
}

// ---------------------------------------------------------------------------
// Detect whether edge_index arrived as int64 (odd int32 words all zero) or int32.
__global__ void detect_kernel(const int* ei, int* flag) {
    if (blockIdx.x == 0 && threadIdx.x == 0) {
        int z = 1;
        for (int k = 0; k < 64; ++k) {
            if (ei[2 * k + 1] != 0) { z = 0; break; }
        }
        *flag = z;  // 1 -> int64 layout
    }
}

// ---------------------------------------------------------------------------
// Init out with the residual (h_scalar | h_vector); accumulation lands on top.
__global__ void init_out(const float* __restrict__ hs, const float* __restrict__ hv,
                         float* __restrict__ out) {
    int i = blockIdx.x * blockDim.x + threadIdx.x;
    if (i >= N_NODESC * (SDIM + VDIM)) return;
    out[i] = (i < N_NODESC * SDIM) ? hs[i] : hv[i - N_NODESC * SDIM];
}

// ---------------------------------------------------------------------------
// Per-node tables: Pp = hs@W1[0:64] + b1, Q = hs@W1[64:128],
// U = hv@W1c, V = hv@W1c' (pair-swapped, sign-flipped). bf16 storage.
__global__ __launch_bounds__(128) void node_precompute(
    const float* __restrict__ hs, const float* __restrict__ hv,
    const float* __restrict__ W1, const float* __restrict__ b1,
    __hip_bfloat16* __restrict__ Pp, __hip_bfloat16* __restrict__ Qt,
    __hip_bfloat16* __restrict__ Ut, __hip_bfloat16* __restrict__ Vt) {
    int n = blockIdx.x;
    __shared__ float s_hs[SDIM];
    __shared__ float s_hv[VDIM];
    int t = threadIdx.x;
    if (t < 64) s_hs[t] = hs[n * SDIM + t];
    else if (t < 96) s_hv[t - 64] = hv[n * VDIM + (t - 64)];
    __syncthreads();
    if (t < HID) {
        float p = b1[t], q = 0.f, u = 0.f, v = 0.f;
        for (int k = 0; k < 64; ++k) {
            float x = s_hs[k];
            p += x * W1[k * HID + t];
            q += x * W1[(64 + k) * HID + t];
        }
        for (int pr = 0; pr < 16; ++pr) {
            float x = s_hv[2 * pr], y = s_hv[2 * pr + 1];
            float wa = W1[(128 + 2 * pr) * HID + t];
            float wb = W1[(128 + 2 * pr + 1) * HID + t];
            u += x * wa + y * wb;
            v += x * wb - y * wa;
        }
        Pp[n * HID + t] = f2bf(p);
        Qt[n * HID + t] = f2bf(q);
        Ut[n * HID + t] = f2bf(u);
        Vt[n * HID + t] = f2bf(v);
    }
}

// ---------------------------------------------------------------------------
// Counting sort by dst: zero counts -> histogram -> scan -> scatter (src,dst int32)
__global__ void zero_counts(int* __restrict__ c) {
    int i = blockIdx.x * blockDim.x + threadIdx.x;
    if (i < N_NODESC) c[i] = 0;
}

__global__ __launch_bounds__(256) void hist_kernel(
    const int* __restrict__ ei, const int* __restrict__ flag64,
    int* __restrict__ counts) {
    int e = blockIdx.x * blockDim.x + threadIdx.x;
    if (e >= N_EDGESC) return;
    int dN;
    if (*flag64) dN = (int)((const long long*)ei)[N_EDGESC + e];
    else dN = ei[N_EDGESC + e];
    atomicAdd(&counts[dN], 1);
}

// Single-block exclusive scan over 50000 counts -> cursor array.
__global__ __launch_bounds__(1024) void scan_kernel(
    const int* __restrict__ counts, int* __restrict__ cur) {
    __shared__ int part[1024];
    const int t = threadIdx.x;
    const int CH = (N_NODESC + 1023) / 1024;  // 49
    int lo = t * CH;
    int hi = lo + CH; if (hi > N_NODESC) hi = N_NODESC;
    int s = 0;
    for (int i = lo; i < hi; ++i) s += counts[i];
    part[t] = s;
    __syncthreads();
    for (int d = 1; d < 1024; d <<= 1) {
        int v = (t >= d) ? part[t - d] : 0;
        __syncthreads();
        part[t] += v;
        __syncthreads();
    }
    int run = (t == 0) ? 0 : part[t - 1];  // exclusive prefix of this chunk
    for (int i = lo; i < hi; ++i) {
        int c = counts[i];
        cur[i] = run;
        run += c;
    }
}

__global__ __launch_bounds__(256) void scatter_kernel(
    const int* __restrict__ ei, const int* __restrict__ flag64,
    int* __restrict__ cur, int* __restrict__ src_s, int* __restrict__ dst_s) {
    int e = blockIdx.x * blockDim.x + threadIdx.x;
    if (e >= N_EDGESC) return;
    int sN, dN;
    if (*flag64) {
        const long long* e64 = (const long long*)ei;
        sN = (int)e64[e]; dN = (int)e64[N_EDGESC + e];
    } else { sN = ei[e]; dN = ei[N_EDGESC + e]; }
    int p = atomicAdd(&cur[dN], 1);
    src_s[p] = sN; dst_s[p] = dN;
}

// ---------------------------------------------------------------------------
// Main edge kernel on dst-sorted edges: 64 edges/tile, layer1 via table combine,
// layer2 via MFMA into an LDS f32 msg tile, then per-dst-segment reduction so
// atomic traffic drops ~21x (avg ~3 segments per 64-edge tile at degree 32).
__global__ __launch_bounds__(256) void edge_kernel_sorted(
    const int* __restrict__ src_s, const int* __restrict__ dst_s,
    const float* __restrict__ pos, const float* __restrict__ ori,
    const float* __restrict__ W1, const float* __restrict__ W2,
    const float* __restrict__ b2,
    const __hip_bfloat16* __restrict__ Pp, const __hip_bfloat16* __restrict__ Qt,
    const __hip_bfloat16* __restrict__ Ut, const __hip_bfloat16* __restrict__ Vt,
    float* __restrict__ out) {
    __shared__ int s_src[64], s_dst[64];
    __shared__ float s_c[64], s_s[64], s_d[64], s_cg[64], s_sg[64];
    __shared__ float s_w1d[3][HID];
    __shared__ __hip_bfloat16 hA[64][104];     // silu(layer1) tile, bf16
    __shared__ float s_msg[64][MPITCH];        // layer2 output tile, f32
    __shared__ int s_segstart[66];
    __shared__ int s_nseg;

    const int t = threadIdx.x;
    const int lane = t & 63;
    const int w = t >> 6;        // wave id 0..3
    const int m16 = lane & 15;
    const int q = lane >> 4;

    // Stage geo weight rows 160..162
    for (int idx = t; idx < 3 * HID; idx += 256) {
        int r = idx / HID, j = idx - r * HID;
        s_w1d[r][j] = W1[(160 + r) * HID + j];
    }

    // Hoist all 18 B fragments of W2 into VGPRs, direct from global (one-time).
    // B-frag layout (16x16x32): lane holds B[k=(lane>>4)*8+jj][n=lane&15]
    s16x8 bfr[6][3];
    for (int nt = 0; nt < 6; ++nt)
        for (int kt = 0; kt < 3; ++kt) {
            s16x8 v;
            for (int jj = 0; jj < 8; ++jj) {
                int k = kt * 32 + q * 8 + jj;
                __hip_bfloat16 hb = f2bf(W2[k * HID + nt * 16 + m16]);
                v[jj] = *(const short*)&hb;
            }
            bfr[nt][kt] = v;
        }
    float b2v[6];
    for (int nt = 0; nt < 6; ++nt) b2v[nt] = b2[nt * 16 + m16];

    for (int tile = blockIdx.x; tile < N_EDGESC / 64; tile += gridDim.x) {
        __syncthreads();  // protect s_* / hA / s_msg from previous iteration

        if (t < 64) {     // exactly wave 0
            int e = tile * 64 + t;
            int sN = src_s[e], dN = dst_s[e];
            s_src[t] = sN; s_dst[t] = dN;
            float ca, sa, cb, sb;
            __sincosf(2.0f * ori[dN], &sa, &ca);
            __sincosf(2.0f * ori[sN], &sb, &cb);
            s_c[t] = cb * ca + sb * sa;   // cos(2(beta-alpha))
            s_s[t] = sb * ca - cb * sa;   // sin(2(beta-alpha))
            float dx = pos[2 * sN] - pos[2 * dN];
            float dy = pos[2 * sN + 1] - pos[2 * dN + 1];
            float d2 = dx * dx + dy * dy;
            s_d[t] = sqrtf(d2) + 1e-6f;
            float c2f, s2f;
            if (d2 > 0.f) {
                float inv = 1.0f / d2;
                c2f = (dx * dx - dy * dy) * inv;  // cos(2phi)
                s2f = 2.0f * dx * dy * inv;       // sin(2phi)
            } else { c2f = 1.0f; s2f = 0.0f; }    // atan2(0,0)=0
            s_cg[t] = c2f * ca + s2f * sa;  // cos(2phi-2alpha)
            s_sg[t] = s2f * ca - c2f * sa;  // sin(2phi-2alpha)

            // Segment structure (dst is non-decreasing within the sorted tile).
            bool bnd = (t > 0) && (dN != s_dst[t - 1]);  // same-wave LDS, ordered
            unsigned long long mask = __ballot(bnd);
            if (bnd) s_segstart[__popcll(mask & (~0ull >> (63 - t)))] = t;
            if (t == 0) s_segstart[0] = 0;
            if (t == 63) {
                int ns = __popcll(mask) + 1;
                s_nseg = ns;
                s_segstart[ns] = 64;
            }
        }
        __syncthreads();

        // Phase 1: h = silu(pre1) for 64 edges x 96 units -> hA (bf16),
        // vectorized: each thread handles 4 consecutive units of one edge.
        for (int p = 0; p < 6; ++p) {
            int item = p * 256 + t;       // < 1536 = 64 edges * 24 j-blocks
            int e = item / 24;
            int jb = item - e * 24;
            int j = jb * 4;
            int sN = s_src[e], dN = s_dst[e];
            s16x4 Pv = *(const s16x4*)&Pp[sN * HID + j];
            s16x4 Qv = *(const s16x4*)&Qt[dN * HID + j];
            s16x4 Uv = *(const s16x4*)&Ut[sN * HID + j];
            s16x4 Vv = *(const s16x4*)&Vt[sN * HID + j];
            float ce = s_c[e], se = s_s[e], de = s_d[e];
            float cge = s_cg[e], sge = s_sg[e];
            s16x4 hb;
            for (int k2 = 0; k2 < 4; ++k2) {
                float pre = bfbits2f(Pv[k2]) + bfbits2f(Qv[k2])
                          + ce * bfbits2f(Uv[k2]) + se * bfbits2f(Vv[k2])
                          + de * s_w1d[0][j + k2] + cge * s_w1d[1][j + k2]
                          + sge * s_w1d[2][j + k2];
                float h = pre / (1.0f + __expf(-pre));  // silu
                __hip_bfloat16 x = f2bf(h);
                hb[k2] = *(const short*)&x;
            }
            *(s16x4*)&hA[e][j] = hb;
        }
        __syncthreads();

        // Phase 2: wave w computes raw_msg for its 16 edges via MFMA -> s_msg f32
        // A-frag: lane holds A[m=lane&15][k=(lane>>4)*8+jj]
        f32x4 acc[6];
        for (int nt = 0; nt < 6; ++nt) acc[nt] = (f32x4){0.f, 0.f, 0.f, 0.f};
        s16x8 afr[3];
        for (int kt = 0; kt < 3; ++kt)
            afr[kt] = *(const s16x8*)&hA[w * 16 + m16][kt * 32 + q * 8];
        for (int nt = 0; nt < 6; ++nt)
            for (int kt = 0; kt < 3; ++kt)
                acc[nt] = __builtin_amdgcn_mfma_f32_16x16x32_bf16(
                    afr[kt], bfr[nt][kt], acc[nt], 0, 0, 0);

        // C/D: col=lane&15 (unit), row=(lane>>4)*4+reg (edge). Bias folded here.
        for (int nt = 0; nt < 6; ++nt) {
            int u = nt * 16 + m16;
            float bb = b2v[nt];
            for (int r = 0; r < 4; ++r) {
                int eloc = w * 16 + q * 4 + r;
                s_msg[eloc][u] = acc[nt][r] + bb;
            }
        }
        __syncthreads();

        // Phase 3: per-segment reduction in LDS, one atomicAdd per (seg, unit).
        int nseg = s_nseg;
        for (int idx = t; idx < nseg * HID; idx += 256) {
            int sg = idx / HID;
            int u = idx - sg * HID;
            int e0 = s_segstart[sg], e1 = s_segstart[sg + 1];
            float sum = 0.f;
            for (int e = e0; e < e1; ++e) sum += s_msg[e][u];
            int dN = s_dst[e0];
            if (u < SDIM) atomicAdd(&out[dN * SDIM + u], sum);
            else atomicAdd(&out[N_NODESC * SDIM + dN * VDIM + (u - SDIM)], sum);
        }
    }
}

// ---------------------------------------------------------------------------
// Mid-tier kernel (tables fit in ws, but no room for the sort arrays):
// identical to previous session's atomic-scatter kernel.
__global__ __launch_bounds__(256) void edge_kernel(
    const int* __restrict__ ei, const float* __restrict__ pos,
    const float* __restrict__ ori, const float* __restrict__ W1,
    const float* __restrict__ W2, const float* __restrict__ b2,
    const __hip_bfloat16* __restrict__ Pp, const __hip_bfloat16* __restrict__ Qt,
    const __hip_bfloat16* __restrict__ Ut, const __hip_bfloat16* __restrict__ Vt,
    const int* __restrict__ flag64, float* __restrict__ out) {
    __shared__ int s_src[64], s_dst[64];
    __shared__ float s_c[64], s_s[64], s_d[64], s_cg[64], s_sg[64];
    __shared__ float s_w1d[3][HID];
    __shared__ __hip_bfloat16 hA[64][104];
    __shared__ __hip_bfloat16 W2T[HID][104];

    const int t = threadIdx.x;
    const int lane = t & 63;
    const int w = t >> 6;
    const int m16 = lane & 15;
    const int q = lane >> 4;

    for (int idx = t; idx < HID * HID; idx += 256) {
        int k = idx / HID;
        int n = idx - k * HID;
        W2T[n][k] = f2bf(W2[idx]);
    }
    for (int idx = t; idx < 3 * HID; idx += 256) {
        int r = idx / HID, j = idx - r * HID;
        s_w1d[r][j] = W1[(160 + r) * HID + j];
    }
    __syncthreads();

    s16x8 bfr[6][3];
    for (int nt = 0; nt < 6; ++nt)
        for (int kt = 0; kt < 3; ++kt)
            bfr[nt][kt] = *(const s16x8*)&W2T[nt * 16 + m16][kt * 32 + q * 8];
    float b2v[6];
    for (int nt = 0; nt < 6; ++nt) b2v[nt] = b2[nt * 16 + m16];

    const bool i64 = (*flag64 != 0);
    const long long* ei64 = (const long long*)ei;

    for (int tile = blockIdx.x; tile < N_EDGESC / 64; tile += gridDim.x) {
        __syncthreads();

        if (t < 64) {
            int e = tile * 64 + t;
            int sN, dN;
            if (i64) { sN = (int)ei64[e]; dN = (int)ei64[N_EDGESC + e]; }
            else     { sN = ei[e];        dN = ei[N_EDGESC + e]; }
            s_src[t] = sN; s_dst[t] = dN;
            float ca, sa, cb, sb;
            __sincosf(2.0f * ori[dN], &sa, &ca);
            __sincosf(2.0f * ori[sN], &sb, &cb);
            s_c[t] = cb * ca + sb * sa;
            s_s[t] = sb * ca - cb * sa;
            float dx = pos[2 * sN] - pos[2 * dN];
            float dy = pos[2 * sN + 1] - pos[2 * dN + 1];
            float d2 = dx * dx + dy * dy;
            s_d[t] = sqrtf(d2) + 1e-6f;
            float c2f, s2f;
            if (d2 > 0.f) {
                float inv = 1.0f / d2;
                c2f = (dx * dx - dy * dy) * inv;
                s2f = 2.0f * dx * dy * inv;
            } else { c2f = 1.0f; s2f = 0.0f; }
            s_cg[t] = c2f * ca + s2f * sa;
            s_sg[t] = s2f * ca - c2f * sa;
        }
        __syncthreads();

        for (int p = 0; p < 24; ++p) {
            int idx = p * 256 + t;
            int e = idx / HID;
            int j = idx - e * HID;
            int sN = s_src[e], dN = s_dst[e];
            float pre = bf2f(Pp[sN * HID + j]) + bf2f(Qt[dN * HID + j])
                      + s_c[e] * bf2f(Ut[sN * HID + j])
                      + s_s[e] * bf2f(Vt[sN * HID + j])
                      + s_d[e] * s_w1d[0][j] + s_cg[e] * s_w1d[1][j]
                      + s_sg[e] * s_w1d[2][j];
            float h = pre / (1.0f + __expf(-pre));
            hA[e][j] = f2bf(h);
        }
        __syncthreads();

        f32x4 acc[6];
        for (int nt = 0; nt < 6; ++nt) acc[nt] = (f32x4){0.f, 0.f, 0.f, 0.f};
        s16x8 afr[3];
        for (int kt = 0; kt < 3; ++kt)
            afr[kt] = *(const s16x8*)&hA[w * 16 + m16][kt * 32 + q * 8];
        for (int nt = 0; nt < 6; ++nt)
            for (int kt = 0; kt < 3; ++kt)
                acc[nt] = __builtin_amdgcn_mfma_f32_16x16x32_bf16(
                    afr[kt], bfr[nt][kt], acc[nt], 0, 0, 0);

        for (int nt = 0; nt < 6; ++nt) {
            int u = nt * 16 + m16;
            for (int r = 0; r < 4; ++r) {
                int eloc = w * 16 + q * 4 + r;
                int dN = s_dst[eloc];
                float val = acc[nt][r] + b2v[nt];
                if (u < SDIM) atomicAdd(&out[dN * SDIM + u], val);
                else atomicAdd(&out[N_NODESC * SDIM + dN * VDIM + (u - SDIM)], val);
            }
        }
    }
}

// ---------------------------------------------------------------------------
// Fallback (ws too small for tables): fully per-edge, correct but slow.
__global__ __launch_bounds__(192) void edge_fallback(
    const int* __restrict__ ei, const float* __restrict__ hs,
    const float* __restrict__ hv, const float* __restrict__ pos,
    const float* __restrict__ ori, const float* __restrict__ W1,
    const float* __restrict__ b1, const float* __restrict__ W2,
    const float* __restrict__ b2, const int* __restrict__ flag64,
    float* __restrict__ out) {
    __shared__ float s_msg[IN_DIMC];
    __shared__ float s_h[HID];
    int e = blockIdx.x;
    int t = threadIdx.x;
    const bool i64 = (*flag64 != 0);
    int sN, dN;
    if (i64) {
        const long long* e64 = (const long long*)ei;
        sN = (int)e64[e]; dN = (int)e64[N_EDGESC + e];
    } else { sN = ei[e]; dN = ei[N_EDGESC + e]; }

    if (t < IN_DIMC) {
        if (t < 64) s_msg[t] = hs[sN * SDIM + t];
        else if (t < 128) s_msg[t] = hs[dN * SDIM + (t - 64)];
        else {
            float ca, sa, cb, sb;
            __sincosf(2.0f * ori[dN], &sa, &ca);
            __sincosf(2.0f * ori[sN], &sb, &cb);
            float c = cb * ca + sb * sa;
            float s = sb * ca - cb * sa;
            float dx = pos[2 * sN] - pos[2 * dN];
            float dy = pos[2 * sN + 1] - pos[2 * dN + 1];
            float d2 = dx * dx + dy * dy;
            if (t < 160) {
                int pr = (t - 128) >> 1;
                float x = hv[sN * VDIM + 2 * pr], y = hv[sN * VDIM + 2 * pr + 1];
                s_msg[t] = ((t & 1) == 0) ? (c * x - s * y) : (s * x + c * y);
            } else if (t == 160) s_msg[t] = sqrtf(d2) + 1e-6f;
            else {
                float c2f = 1.0f, s2f = 0.0f;
                if (d2 > 0.f) {
                    float inv = 1.0f / d2;
                    c2f = (dx * dx - dy * dy) * inv;
                    s2f = 2.0f * dx * dy * inv;
                }
                s_msg[t] = (t == 161) ? (c2f * ca + s2f * sa) : (s2f * ca - c2f * sa);
            }
        }
    }
    __syncthreads();
    if (t < HID) {
        float a = b1[t];
        for (int k = 0; k < IN_DIMC; ++k) a += s_msg[k] * W1[k * HID + t];
        s_h[t] = a / (1.0f + __expf(-a));
    }
    __syncthreads();
    if (t < HID) {
        float a = b2[t];
        for (int k = 0; k < HID; ++k) a += s_h[k] * W2[k * HID + t];
        if (t < SDIM) atomicAdd(&out[dN * SDIM + t], a);
        else atomicAdd(&out[N_NODESC * SDIM + dN * VDIM + (t - SDIM)], a);
    }
}

// ---------------------------------------------------------------------------
extern "C" void kernel_launch(void* const* d_in, const int* in_sizes, int n_in,
                              void* d_out, int out_size, void* d_ws, size_t ws_size,
                              hipStream_t stream) {
    const float* hs  = (const float*)d_in[0];
    const float* hv  = (const float*)d_in[1];
    const int*   ei  = (const int*)d_in[2];
    const float* pos = (const float*)d_in[3];
    const float* ori = (const float*)d_in[4];
    const float* W1  = (const float*)d_in[5];
    const float* b1  = (const float*)d_in[6];
    const float* W2  = (const float*)d_in[7];
    const float* b2  = (const float*)d_in[8];
    float* out = (float*)d_out;

    const size_t TBL = (size_t)N_NODESC * HID * sizeof(__hip_bfloat16);  // 9.6 MB
    const size_t CNT = (size_t)N_NODESC * sizeof(int);                   // 200 KB
    const size_t EDG = (size_t)N_EDGESC * sizeof(int);                   // 6.4 MB
    const size_t SORT_WS = 4 * TBL + 64 + 2 * CNT + 2 * EDG;             // ~51.6 MB
    const bool big  = ws_size >= 4 * TBL + 16;
    const bool srt  = ws_size >= SORT_WS;

    init_out<<<(N_NODESC * (SDIM + VDIM) + 255) / 256, 256, 0, stream>>>(hs, hv, out);

    if (srt) {
        char* ws = (char*)d_ws;
        __hip_bfloat16* Pp = (__hip_bfloat16*)(ws);
        __hip_bfloat16* Qt = (__hip_bfloat16*)(ws + TBL);
        __hip_bfloat16* Ut = (__hip_bfloat16*)(ws + 2 * TBL);
        __hip_bfloat16* Vt = (__hip_bfloat16*)(ws + 3 * TBL);
        int* flag   = (int*)(ws + 4 * TBL);
        int* counts = (int*)(ws + 4 * TBL + 64);
        int* cur    = (int*)(ws + 4 * TBL + 64 + CNT);
        int* src_s  = (int*)(ws + 4 * TBL + 64 + 2 * CNT);
        int* dst_s  = (int*)(ws + 4 * TBL + 64 + 2 * CNT + EDG);

        detect_kernel<<<1, 64, 0, stream>>>(ei, flag);
        node_precompute<<<N_NODESC, 128, 0, stream>>>(hs, hv, W1, b1, Pp, Qt, Ut, Vt);
        zero_counts<<<(N_NODESC + 255) / 256, 256, 0, stream>>>(counts);
        hist_kernel<<<N_EDGESC / 256, 256, 0, stream>>>(ei, flag, counts);
        scan_kernel<<<1, 1024, 0, stream>>>(counts, cur);
        scatter_kernel<<<N_EDGESC / 256, 256, 0, stream>>>(ei, flag, cur, src_s, dst_s);
        edge_kernel_sorted<<<2500, 256, 0, stream>>>(src_s, dst_s, pos, ori, W1, W2,
                                                     b2, Pp, Qt, Ut, Vt, out);
    } else if (big) {
        char* ws = (char*)d_ws;
        __hip_bfloat16* Pp = (__hip_bfloat16*)(ws);
        __hip_bfloat16* Qt = (__hip_bfloat16*)(ws + TBL);
        __hip_bfloat16* Ut = (__hip_bfloat16*)(ws + 2 * TBL);
        __hip_bfloat16* Vt = (__hip_bfloat16*)(ws + 3 * TBL);
        int* flag = (int*)(ws + 4 * TBL);
        detect_kernel<<<1, 64, 0, stream>>>(ei, flag);
        node_precompute<<<N_NODESC, 128, 0, stream>>>(hs, hv, W1, b1, Pp, Qt, Ut, Vt);
        edge_kernel<<<2500, 256, 0, stream>>>(ei, pos, ori, W1, W2, b2,
                                              Pp, Qt, Ut, Vt, flag, out);
    } else {
        int* flag = (int*)d_ws;
        detect_kernel<<<1, 64, 0, stream>>>(ei, flag);
        edge_fallback<<<N_EDGESC, 192, 0, stream>>>(ei, hs, hv, pos, ori, W1, b1,
                                                    W2, b2, flag, out);
    }
}

// Round 2
// 752.267 us; speedup vs baseline: 1.1173x; 1.0968x over previous
//
#include <hip/hip_runtime.h>
#include <hip/hip_bf16.h>

#define N_NODESC 50000
#define N_EDGESC 1600000
#define SDIM 64
#define VDIM 32
#define HID 96
#define IN_DIMC 163

typedef float f32x4 __attribute__((ext_vector_type(4)));
typedef short s16x8 __attribute__((ext_vector_type(8)));
typedef short s16x4 __attribute__((ext_vector_type(4)));

__device__ __forceinline__ float bf2f(__hip_bfloat16 x) { return __bfloat162float(x); }
__device__ __forceinline__ __hip_bfloat16 f2bf(float x) { return __float2bfloat16(x); }
__device__ __forceinline__ float bfbits2f(short b) {
    unsigned u = ((unsigned)(unsigned short)b) << 16;
    return __builtin_bit_cast(float, u);
}

// ---------------------------------------------------------------------------
// Detect whether edge_index arrived as int64 (odd int32 words all zero) or int32.
__global__ void detect_kernel(const int* ei, int* flag) {
    if (blockIdx.x == 0 && threadIdx.x == 0) {
        int z = 1;
        for (int k = 0; k < 64; ++k) {
            if (ei[2 * k + 1] != 0) { z = 0; break; }
        }
        *flag = z;  // 1 -> int64 layout
    }
}

// ---------------------------------------------------------------------------
// Fused one-shot prep: residual init of out, zero counts, detect int64 layout,
// build W_bigT (bf16, [384][96]: P/Q/U/V weight blocks, K-major per row) and
// W2T bf16 ([96][96], W2T[n][k] = W2[k][n]).
__global__ void fused_init(const float* __restrict__ hs, const float* __restrict__ hv,
                           float* __restrict__ out, int* __restrict__ counts,
                           const float* __restrict__ W1, const float* __restrict__ W2,
                           __hip_bfloat16* __restrict__ WbT,
                           __hip_bfloat16* __restrict__ W2Tb,
                           const int* __restrict__ ei, int* __restrict__ flag) {
    int i = blockIdx.x * blockDim.x + threadIdx.x;
    if (i < N_NODESC * (SDIM + VDIM))
        out[i] = (i < N_NODESC * SDIM) ? hs[i] : hv[i - N_NODESC * SDIM];
    if (i < N_NODESC) counts[i] = 0;
    if (i < 384 * 96) {
        int n = i / 96, k = i - (i / 96) * 96;
        int blk = n / 96, j = n - blk * 96;
        float val = 0.f;
        if (blk == 0)      { if (k < 64)  val = W1[k * HID + j]; }
        else if (blk == 1) { if (k < 64)  val = W1[(64 + k) * HID + j]; }
        else if (blk == 2) { if (k >= 64) val = W1[(128 + (k - 64)) * HID + j]; }
        else {
            if (k >= 64) {
                int kk = k - 64;  // even kk=2p -> wb=W1[129+kk]; odd kk -> -wa=-W1[127+kk]
                val = (kk & 1) ? -W1[(127 + kk) * HID + j] : W1[(129 + kk) * HID + j];
            }
        }
        WbT[i] = f2bf(val);
    }
    if (i < 96 * 96) {
        int n = i / 96, k = i - (i / 96) * 96;
        W2Tb[i] = f2bf(W2[k * HID + n]);
    }
    if (i == 0) {
        int z = 1;
        for (int kk = 0; kk < 64; ++kk) if (ei[2 * kk + 1] != 0) { z = 0; break; }
        *flag = z;
    }
}

// ---------------------------------------------------------------------------
// MFMA node precompute: C[50000 x 384] = [hs|hv]_bf16 @ W_big, wave w of each
// block owns output table w (0=Pp(+b1),1=Qt,2=Ut,3=Vt). 64 nodes per block.
__global__ __launch_bounds__(256, 2) void node_precompute_mfma(
    const float* __restrict__ hs, const float* __restrict__ hv,
    const __hip_bfloat16* __restrict__ WbT, const float* __restrict__ b1,
    __hip_bfloat16* __restrict__ Pp, __hip_bfloat16* __restrict__ Qt,
    __hip_bfloat16* __restrict__ Ut, __hip_bfloat16* __restrict__ Vt) {
    __shared__ __hip_bfloat16 sA[64][104];
    const int t = threadIdx.x;
    const int lane = t & 63;
    const int w = t >> 6;
    const int m16 = lane & 15;
    const int q = lane >> 4;
    const int nb = blockIdx.x * 64;

    for (int idx = t; idx < 64 * 64; idx += 256) {
        int node = idx >> 6, f = idx & 63;
        int g = nb + node;
        sA[node][f] = f2bf(g < N_NODESC ? hs[g * SDIM + f] : 0.f);
    }
    for (int idx = t; idx < 64 * 32; idx += 256) {
        int node = idx >> 5, f = idx & 31;
        int g = nb + node;
        sA[node][64 + f] = f2bf(g < N_NODESC ? hv[g * VDIM + f] : 0.f);
    }
    __syncthreads();

    // B-frags for this wave's N-strip [w*96, w*96+96)
    s16x8 bfr[6][3];
    for (int nt = 0; nt < 6; ++nt)
        for (int kt = 0; kt < 3; ++kt)
            bfr[nt][kt] = *(const s16x8*)&WbT[(w * 96 + nt * 16 + m16) * 96 + kt * 32 + q * 8];
    float b1v[6];
    for (int nt = 0; nt < 6; ++nt) b1v[nt] = (w == 0) ? b1[nt * 16 + m16] : 0.f;
    __hip_bfloat16* T = (w == 0) ? Pp : (w == 1) ? Qt : (w == 2) ? Ut : Vt;

    for (int ms = 0; ms < 4; ++ms) {
        s16x8 afr[3];
        for (int kt = 0; kt < 3; ++kt)
            afr[kt] = *(const s16x8*)&sA[ms * 16 + m16][kt * 32 + q * 8];
        f32x4 acc[6];
        for (int nt = 0; nt < 6; ++nt) acc[nt] = (f32x4){0.f, 0.f, 0.f, 0.f};
        for (int nt = 0; nt < 6; ++nt)
            for (int kt = 0; kt < 3; ++kt)
                acc[nt] = __builtin_amdgcn_mfma_f32_16x16x32_bf16(
                    afr[kt], bfr[nt][kt], acc[nt], 0, 0, 0);
        for (int nt = 0; nt < 6; ++nt) {
            int j = nt * 16 + m16;
            for (int r = 0; r < 4; ++r) {
                int node = nb + ms * 16 + q * 4 + r;
                if (node < N_NODESC) T[node * HID + j] = f2bf(acc[nt][r] + b1v[nt]);
            }
        }
    }
}

// ---------------------------------------------------------------------------
// Counting sort by dst.
__global__ __launch_bounds__(256) void hist_kernel(
    const int* __restrict__ ei, const int* __restrict__ flag64,
    int* __restrict__ counts) {
    int e = blockIdx.x * blockDim.x + threadIdx.x;
    if (e >= N_EDGESC) return;
    int dN;
    if (*flag64) dN = (int)((const long long*)ei)[N_EDGESC + e];
    else dN = ei[N_EDGESC + e];
    atomicAdd(&counts[dN], 1);
}

// Single-block exclusive scan over 50000 counts -> cursor array.
__global__ __launch_bounds__(1024) void scan_kernel(
    const int* __restrict__ counts, int* __restrict__ cur) {
    __shared__ int part[1024];
    const int t = threadIdx.x;
    const int CH = (N_NODESC + 1023) / 1024;  // 49
    int lo = t * CH;
    int hi = lo + CH; if (hi > N_NODESC) hi = N_NODESC;
    int s = 0;
    for (int i = lo; i < hi; ++i) s += counts[i];
    part[t] = s;
    __syncthreads();
    for (int d = 1; d < 1024; d <<= 1) {
        int v = (t >= d) ? part[t - d] : 0;
        __syncthreads();
        part[t] += v;
        __syncthreads();
    }
    int run = (t == 0) ? 0 : part[t - 1];
    for (int i = lo; i < hi; ++i) {
        int c = counts[i];
        cur[i] = run;
        run += c;
    }
}

__global__ __launch_bounds__(256) void scatter_kernel(
    const int* __restrict__ ei, const int* __restrict__ flag64,
    int* __restrict__ cur, int2* __restrict__ edges) {
    int e = blockIdx.x * blockDim.x + threadIdx.x;
    if (e >= N_EDGESC) return;
    int sN, dN;
    if (*flag64) {
        const long long* e64 = (const long long*)ei;
        sN = (int)e64[e]; dN = (int)e64[N_EDGESC + e];
    } else { sN = ei[e]; dN = ei[N_EDGESC + e]; }
    int p = atomicAdd(&cur[dN], 1);
    edges[p] = make_int2(sN, dN);
}

// ---------------------------------------------------------------------------
// Main edge kernel on dst-sorted edges: 64 edges/tile, layer1 via table combine,
// layer2 via MFMA into an LDS bf16 msg tile, per-dst-segment reduction.
__global__ __launch_bounds__(256, 4) void edge_kernel_sorted(
    const int2* __restrict__ edges,
    const float* __restrict__ pos, const float* __restrict__ ori,
    const float* __restrict__ W1, const __hip_bfloat16* __restrict__ W2Tb,
    const float* __restrict__ b2,
    const __hip_bfloat16* __restrict__ Pp, const __hip_bfloat16* __restrict__ Qt,
    const __hip_bfloat16* __restrict__ Ut, const __hip_bfloat16* __restrict__ Vt,
    float* __restrict__ out) {
    __shared__ int s_src[64], s_dst[64];
    __shared__ float s_c[64], s_s[64], s_d[64], s_cg[64], s_sg[64];
    __shared__ float s_w1d[3][HID];
    __shared__ __hip_bfloat16 hA[64][104];     // silu(layer1) tile, bf16
    __shared__ __hip_bfloat16 s_msgb[64][100]; // layer2 output tile, bf16
    __shared__ int s_segstart[66];
    __shared__ int s_nseg;

    const int t = threadIdx.x;
    const int lane = t & 63;
    const int w = t >> 6;        // wave id 0..3
    const int m16 = lane & 15;
    const int q = lane >> 4;

    // Stage geo weight rows 160..162
    for (int idx = t; idx < 3 * HID; idx += 256) {
        int r = idx / HID, j = idx - r * HID;
        s_w1d[r][j] = W1[(160 + r) * HID + j];
    }

    // Hoist all 18 B fragments of W2 into VGPRs (16B vector loads from W2Tb).
    // B-frag layout (16x16x32): lane holds B[k=(lane>>4)*8+jj][n=lane&15]
    s16x8 bfr[6][3];
    for (int nt = 0; nt < 6; ++nt)
        for (int kt = 0; kt < 3; ++kt)
            bfr[nt][kt] = *(const s16x8*)&W2Tb[(nt * 16 + m16) * 96 + kt * 32 + q * 8];
    float b2v[6];
    for (int nt = 0; nt < 6; ++nt) b2v[nt] = b2[nt * 16 + m16];

    for (int tile = blockIdx.x; tile < N_EDGESC / 64; tile += gridDim.x) {
        __syncthreads();  // protect s_* / hA / s_msgb from previous iteration

        if (t < 64) {     // exactly wave 0
            int2 ed = edges[tile * 64 + t];
            int sN = ed.x, dN = ed.y;
            s_src[t] = sN; s_dst[t] = dN;
            float ca, sa, cb, sb;
            __sincosf(2.0f * ori[dN], &sa, &ca);
            __sincosf(2.0f * ori[sN], &sb, &cb);
            s_c[t] = cb * ca + sb * sa;   // cos(2(beta-alpha))
            s_s[t] = sb * ca - cb * sa;   // sin(2(beta-alpha))
            float dx = pos[2 * sN] - pos[2 * dN];
            float dy = pos[2 * sN + 1] - pos[2 * dN + 1];
            float d2 = dx * dx + dy * dy;
            s_d[t] = sqrtf(d2) + 1e-6f;
            float c2f, s2f;
            if (d2 > 0.f) {
                float inv = 1.0f / d2;
                c2f = (dx * dx - dy * dy) * inv;  // cos(2phi)
                s2f = 2.0f * dx * dy * inv;       // sin(2phi)
            } else { c2f = 1.0f; s2f = 0.0f; }    // atan2(0,0)=0
            s_cg[t] = c2f * ca + s2f * sa;  // cos(2phi-2alpha)
            s_sg[t] = s2f * ca - c2f * sa;  // sin(2phi-2alpha)

            // Segment structure (dst is non-decreasing within the sorted tile).
            bool bnd = (t > 0) && (dN != s_dst[t - 1]);  // same-wave LDS, ordered
            unsigned long long mask = __ballot(bnd);
            if (bnd) s_segstart[__popcll(mask & (~0ull >> (63 - t)))] = t;
            if (t == 0) s_segstart[0] = 0;
            if (t == 63) {
                int ns = __popcll(mask) + 1;
                s_nseg = ns;
                s_segstart[ns] = 64;
            }
        }
        __syncthreads();

        // Phase 1: h = silu(pre1) for 64 edges x 96 units -> hA (bf16),
        // vectorized: each thread handles 8 consecutive units of one edge (16B loads).
        for (int p = 0; p < 3; ++p) {
            int item = p * 256 + t;       // < 768 = 64 edges * 12 j-blocks
            int e = item / 12;
            int jb = item - e * 12;
            int j = jb * 8;
            int sN = s_src[e], dN = s_dst[e];
            s16x8 Pv = *(const s16x8*)&Pp[sN * HID + j];
            s16x8 Qv = *(const s16x8*)&Qt[dN * HID + j];
            s16x8 Uv = *(const s16x8*)&Ut[sN * HID + j];
            s16x8 Vv = *(const s16x8*)&Vt[sN * HID + j];
            float ce = s_c[e], se = s_s[e], de = s_d[e];
            float cge = s_cg[e], sge = s_sg[e];
            s16x8 hb;
            for (int k2 = 0; k2 < 8; ++k2) {
                float pre = bfbits2f(Pv[k2]) + bfbits2f(Qv[k2])
                          + ce * bfbits2f(Uv[k2]) + se * bfbits2f(Vv[k2])
                          + de * s_w1d[0][j + k2] + cge * s_w1d[1][j + k2]
                          + sge * s_w1d[2][j + k2];
                float h = pre / (1.0f + __expf(-pre));  // silu
                __hip_bfloat16 x = f2bf(h);
                hb[k2] = *(const short*)&x;
            }
            *(s16x8*)&hA[e][j] = hb;
        }
        __syncthreads();

        // Phase 2: wave w computes raw_msg for its 16 edges via MFMA -> s_msgb
        // A-frag: lane holds A[m=lane&15][k=(lane>>4)*8+jj]
        f32x4 acc[6];
        for (int nt = 0; nt < 6; ++nt) acc[nt] = (f32x4){0.f, 0.f, 0.f, 0.f};
        s16x8 afr[3];
        for (int kt = 0; kt < 3; ++kt)
            afr[kt] = *(const s16x8*)&hA[w * 16 + m16][kt * 32 + q * 8];
        for (int nt = 0; nt < 6; ++nt)
            for (int kt = 0; kt < 3; ++kt)
                acc[nt] = __builtin_amdgcn_mfma_f32_16x16x32_bf16(
                    afr[kt], bfr[nt][kt], acc[nt], 0, 0, 0);

        // C/D: col=lane&15 (unit), row=(lane>>4)*4+reg (edge). Bias folded here.
        for (int nt = 0; nt < 6; ++nt) {
            int u = nt * 16 + m16;
            float bb = b2v[nt];
            for (int r = 0; r < 4; ++r) {
                int eloc = w * 16 + q * 4 + r;
                s_msgb[eloc][u] = f2bf(acc[nt][r] + bb);
            }
        }
        __syncthreads();

        // Phase 3: per-segment reduction in LDS, one atomicAdd per (seg, unit).
        int nseg = s_nseg;
        for (int idx = t; idx < nseg * HID; idx += 256) {
            int sg = idx / HID;
            int u = idx - sg * HID;
            int e0 = s_segstart[sg], e1 = s_segstart[sg + 1];
            float sum = 0.f;
            for (int e = e0; e < e1; ++e) sum += bf2f(s_msgb[e][u]);
            int dN = s_dst[e0];
            if (u < SDIM) atomicAdd(&out[dN * SDIM + u], sum);
            else atomicAdd(&out[N_NODESC * SDIM + dN * VDIM + (u - SDIM)], sum);
        }
    }
}

// ---------------------------------------------------------------------------
// Mid-tier: f32 per-node precompute (exact), used when ws can't hold sort arrays.
__global__ __launch_bounds__(128) void node_precompute(
    const float* __restrict__ hs, const float* __restrict__ hv,
    const float* __restrict__ W1, const float* __restrict__ b1,
    __hip_bfloat16* __restrict__ Pp, __hip_bfloat16* __restrict__ Qt,
    __hip_bfloat16* __restrict__ Ut, __hip_bfloat16* __restrict__ Vt) {
    int n = blockIdx.x;
    __shared__ float s_hs[SDIM];
    __shared__ float s_hv[VDIM];
    int t = threadIdx.x;
    if (t < 64) s_hs[t] = hs[n * SDIM + t];
    else if (t < 96) s_hv[t - 64] = hv[n * VDIM + (t - 64)];
    __syncthreads();
    if (t < HID) {
        float p = b1[t], qq = 0.f, u = 0.f, v = 0.f;
        for (int k = 0; k < 64; ++k) {
            float x = s_hs[k];
            p += x * W1[k * HID + t];
            qq += x * W1[(64 + k) * HID + t];
        }
        for (int pr = 0; pr < 16; ++pr) {
            float x = s_hv[2 * pr], y = s_hv[2 * pr + 1];
            float wa = W1[(128 + 2 * pr) * HID + t];
            float wb = W1[(128 + 2 * pr + 1) * HID + t];
            u += x * wa + y * wb;
            v += x * wb - y * wa;
        }
        Pp[n * HID + t] = f2bf(p);
        Qt[n * HID + t] = f2bf(qq);
        Ut[n * HID + t] = f2bf(u);
        Vt[n * HID + t] = f2bf(v);
    }
}

__global__ void init_out(const float* __restrict__ hs, const float* __restrict__ hv,
                         float* __restrict__ out) {
    int i = blockIdx.x * blockDim.x + threadIdx.x;
    if (i >= N_NODESC * (SDIM + VDIM)) return;
    out[i] = (i < N_NODESC * SDIM) ? hs[i] : hv[i - N_NODESC * SDIM];
}

// Mid-tier edge kernel (unsorted, atomic scatter) — round-0 version.
__global__ __launch_bounds__(256) void edge_kernel(
    const int* __restrict__ ei, const float* __restrict__ pos,
    const float* __restrict__ ori, const float* __restrict__ W1,
    const float* __restrict__ W2, const float* __restrict__ b2,
    const __hip_bfloat16* __restrict__ Pp, const __hip_bfloat16* __restrict__ Qt,
    const __hip_bfloat16* __restrict__ Ut, const __hip_bfloat16* __restrict__ Vt,
    const int* __restrict__ flag64, float* __restrict__ out) {
    __shared__ int s_src[64], s_dst[64];
    __shared__ float s_c[64], s_s[64], s_d[64], s_cg[64], s_sg[64];
    __shared__ float s_w1d[3][HID];
    __shared__ __hip_bfloat16 hA[64][104];
    __shared__ __hip_bfloat16 W2T[HID][104];

    const int t = threadIdx.x;
    const int lane = t & 63;
    const int w = t >> 6;
    const int m16 = lane & 15;
    const int q = lane >> 4;

    for (int idx = t; idx < HID * HID; idx += 256) {
        int k = idx / HID;
        int n = idx - k * HID;
        W2T[n][k] = f2bf(W2[idx]);
    }
    for (int idx = t; idx < 3 * HID; idx += 256) {
        int r = idx / HID, j = idx - r * HID;
        s_w1d[r][j] = W1[(160 + r) * HID + j];
    }
    __syncthreads();

    s16x8 bfr[6][3];
    for (int nt = 0; nt < 6; ++nt)
        for (int kt = 0; kt < 3; ++kt)
            bfr[nt][kt] = *(const s16x8*)&W2T[nt * 16 + m16][kt * 32 + q * 8];
    float b2v[6];
    for (int nt = 0; nt < 6; ++nt) b2v[nt] = b2[nt * 16 + m16];

    const bool i64 = (*flag64 != 0);
    const long long* ei64 = (const long long*)ei;

    for (int tile = blockIdx.x; tile < N_EDGESC / 64; tile += gridDim.x) {
        __syncthreads();

        if (t < 64) {
            int e = tile * 64 + t;
            int sN, dN;
            if (i64) { sN = (int)ei64[e]; dN = (int)ei64[N_EDGESC + e]; }
            else     { sN = ei[e];        dN = ei[N_EDGESC + e]; }
            s_src[t] = sN; s_dst[t] = dN;
            float ca, sa, cb, sb;
            __sincosf(2.0f * ori[dN], &sa, &ca);
            __sincosf(2.0f * ori[sN], &sb, &cb);
            s_c[t] = cb * ca + sb * sa;
            s_s[t] = sb * ca - cb * sa;
            float dx = pos[2 * sN] - pos[2 * dN];
            float dy = pos[2 * sN + 1] - pos[2 * dN + 1];
            float d2 = dx * dx + dy * dy;
            s_d[t] = sqrtf(d2) + 1e-6f;
            float c2f, s2f;
            if (d2 > 0.f) {
                float inv = 1.0f / d2;
                c2f = (dx * dx - dy * dy) * inv;
                s2f = 2.0f * dx * dy * inv;
            } else { c2f = 1.0f; s2f = 0.0f; }
            s_cg[t] = c2f * ca + s2f * sa;
            s_sg[t] = s2f * ca - c2f * sa;
        }
        __syncthreads();

        for (int p = 0; p < 24; ++p) {
            int idx = p * 256 + t;
            int e = idx / HID;
            int j = idx - e * HID;
            int sN = s_src[e], dN = s_dst[e];
            float pre = bf2f(Pp[sN * HID + j]) + bf2f(Qt[dN * HID + j])
                      + s_c[e] * bf2f(Ut[sN * HID + j])
                      + s_s[e] * bf2f(Vt[sN * HID + j])
                      + s_d[e] * s_w1d[0][j] + s_cg[e] * s_w1d[1][j]
                      + s_sg[e] * s_w1d[2][j];
            float h = pre / (1.0f + __expf(-pre));
            hA[e][j] = f2bf(h);
        }
        __syncthreads();

        f32x4 acc[6];
        for (int nt = 0; nt < 6; ++nt) acc[nt] = (f32x4){0.f, 0.f, 0.f, 0.f};
        s16x8 afr[3];
        for (int kt = 0; kt < 3; ++kt)
            afr[kt] = *(const s16x8*)&hA[w * 16 + m16][kt * 32 + q * 8];
        for (int nt = 0; nt < 6; ++nt)
            for (int kt = 0; kt < 3; ++kt)
                acc[nt] = __builtin_amdgcn_mfma_f32_16x16x32_bf16(
                    afr[kt], bfr[nt][kt], acc[nt], 0, 0, 0);

        for (int nt = 0; nt < 6; ++nt) {
            int u = nt * 16 + m16;
            for (int r = 0; r < 4; ++r) {
                int eloc = w * 16 + q * 4 + r;
                int dN = s_dst[eloc];
                float val = acc[nt][r] + b2v[nt];
                if (u < SDIM) atomicAdd(&out[dN * SDIM + u], val);
                else atomicAdd(&out[N_NODESC * SDIM + dN * VDIM + (u - SDIM)], val);
            }
        }
    }
}

// ---------------------------------------------------------------------------
// Fallback (ws too small for tables): fully per-edge, correct but slow.
__global__ __launch_bounds__(192) void edge_fallback(
    const int* __restrict__ ei, const float* __restrict__ hs,
    const float* __restrict__ hv, const float* __restrict__ pos,
    const float* __restrict__ ori, const float* __restrict__ W1,
    const float* __restrict__ b1, const float* __restrict__ W2,
    const float* __restrict__ b2, const int* __restrict__ flag64,
    float* __restrict__ out) {
    __shared__ float s_msg[IN_DIMC];
    __shared__ float s_h[HID];
    int e = blockIdx.x;
    int t = threadIdx.x;
    const bool i64 = (*flag64 != 0);
    int sN, dN;
    if (i64) {
        const long long* e64 = (const long long*)ei;
        sN = (int)e64[e]; dN = (int)e64[N_EDGESC + e];
    } else { sN = ei[e]; dN = ei[N_EDGESC + e]; }

    if (t < IN_DIMC) {
        if (t < 64) s_msg[t] = hs[sN * SDIM + t];
        else if (t < 128) s_msg[t] = hs[dN * SDIM + (t - 64)];
        else {
            float ca, sa, cb, sb;
            __sincosf(2.0f * ori[dN], &sa, &ca);
            __sincosf(2.0f * ori[sN], &sb, &cb);
            float c = cb * ca + sb * sa;
            float s = sb * ca - cb * sa;
            float dx = pos[2 * sN] - pos[2 * dN];
            float dy = pos[2 * sN + 1] - pos[2 * dN + 1];
            float d2 = dx * dx + dy * dy;
            if (t < 160) {
                int pr = (t - 128) >> 1;
                float x = hv[sN * VDIM + 2 * pr], y = hv[sN * VDIM + 2 * pr + 1];
                s_msg[t] = ((t & 1) == 0) ? (c * x - s * y) : (s * x + c * y);
            } else if (t == 160) s_msg[t] = sqrtf(d2) + 1e-6f;
            else {
                float c2f = 1.0f, s2f = 0.0f;
                if (d2 > 0.f) {
                    float inv = 1.0f / d2;
                    c2f = (dx * dx - dy * dy) * inv;
                    s2f = 2.0f * dx * dy * inv;
                }
                s_msg[t] = (t == 161) ? (c2f * ca + s2f * sa) : (s2f * ca - c2f * sa);
            }
        }
    }
    __syncthreads();
    if (t < HID) {
        float a = b1[t];
        for (int k = 0; k < IN_DIMC; ++k) a += s_msg[k] * W1[k * HID + t];
        s_h[t] = a / (1.0f + __expf(-a));
    }
    __syncthreads();
    if (t < HID) {
        float a = b2[t];
        for (int k = 0; k < HID; ++k) a += s_h[k] * W2[k * HID + t];
        if (t < SDIM) atomicAdd(&out[dN * SDIM + t], a);
        else atomicAdd(&out[N_NODESC * SDIM + dN * VDIM + (t - SDIM)], a);
    }
}

// ---------------------------------------------------------------------------
extern "C" void kernel_launch(void* const* d_in, const int* in_sizes, int n_in,
                              void* d_out, int out_size, void* d_ws, size_t ws_size,
                              hipStream_t stream) {
    const float* hs  = (const float*)d_in[0];
    const float* hv  = (const float*)d_in[1];
    const int*   ei  = (const int*)d_in[2];
    const float* pos = (const float*)d_in[3];
    const float* ori = (const float*)d_in[4];
    const float* W1  = (const float*)d_in[5];
    const float* b1  = (const float*)d_in[6];
    const float* W2  = (const float*)d_in[7];
    const float* b2  = (const float*)d_in[8];
    float* out = (float*)d_out;

    const size_t TBL = (size_t)N_NODESC * HID * sizeof(__hip_bfloat16);  // 9.6 MB
    const size_t CNT = (size_t)N_NODESC * sizeof(int);                   // 200 KB
    const size_t EDG = (size_t)N_EDGESC * sizeof(int);                   // 6.4 MB
    const size_t WBT = (size_t)384 * 96 * sizeof(__hip_bfloat16);        // 73.7 KB
    const size_t W2T = (size_t)96 * 96 * sizeof(__hip_bfloat16);         // 18.4 KB
    const size_t SORT_WS = 4 * TBL + 64 + 2 * CNT + 2 * EDG + WBT + W2T; // ~51.8 MB
    const bool big  = ws_size >= 4 * TBL + 16;
    const bool srt  = ws_size >= SORT_WS;

    if (srt) {
        char* ws = (char*)d_ws;
        __hip_bfloat16* Pp = (__hip_bfloat16*)(ws);
        __hip_bfloat16* Qt = (__hip_bfloat16*)(ws + TBL);
        __hip_bfloat16* Ut = (__hip_bfloat16*)(ws + 2 * TBL);
        __hip_bfloat16* Vt = (__hip_bfloat16*)(ws + 3 * TBL);
        int* flag   = (int*)(ws + 4 * TBL);
        int* counts = (int*)(ws + 4 * TBL + 64);
        int* cur    = (int*)(ws + 4 * TBL + 64 + CNT);
        int2* edges = (int2*)(ws + 4 * TBL + 64 + 2 * CNT);
        __hip_bfloat16* WbT  = (__hip_bfloat16*)(ws + 4 * TBL + 64 + 2 * CNT + 2 * EDG);
        __hip_bfloat16* W2Tb = (__hip_bfloat16*)(ws + 4 * TBL + 64 + 2 * CNT + 2 * EDG + WBT);

        fused_init<<<(N_NODESC * (SDIM + VDIM) + 255) / 256, 256, 0, stream>>>(
            hs, hv, out, counts, W1, W2, WbT, W2Tb, ei, flag);
        hist_kernel<<<N_EDGESC / 256, 256, 0, stream>>>(ei, flag, counts);
        scan_kernel<<<1, 1024, 0, stream>>>(counts, cur);
        scatter_kernel<<<N_EDGESC / 256, 256, 0, stream>>>(ei, flag, cur, edges);
        node_precompute_mfma<<<(N_NODESC + 63) / 64, 256, 0, stream>>>(
            hs, hv, WbT, b1, Pp, Qt, Ut, Vt);
        edge_kernel_sorted<<<2500, 256, 0, stream>>>(edges, pos, ori, W1, W2Tb, b2,
                                                     Pp, Qt, Ut, Vt, out);
    } else if (big) {
        char* ws = (char*)d_ws;
        __hip_bfloat16* Pp = (__hip_bfloat16*)(ws);
        __hip_bfloat16* Qt = (__hip_bfloat16*)(ws + TBL);
        __hip_bfloat16* Ut = (__hip_bfloat16*)(ws + 2 * TBL);
        __hip_bfloat16* Vt = (__hip_bfloat16*)(ws + 3 * TBL);
        int* flag = (int*)(ws + 4 * TBL);
        init_out<<<(N_NODESC * (SDIM + VDIM) + 255) / 256, 256, 0, stream>>>(hs, hv, out);
        detect_kernel<<<1, 64, 0, stream>>>(ei, flag);
        node_precompute<<<N_NODESC, 128, 0, stream>>>(hs, hv, W1, b1, Pp, Qt, Ut, Vt);
        edge_kernel<<<2500, 256, 0, stream>>>(ei, pos, ori, W1, W2, b2,
                                              Pp, Qt, Ut, Vt, flag, out);
    } else {
        int* flag = (int*)d_ws;
        init_out<<<(N_NODESC * (SDIM + VDIM) + 255) / 256, 256, 0, stream>>>(hs, hv, out);
        detect_kernel<<<1, 64, 0, stream>>>(ei, flag);
        edge_fallback<<<N_EDGESC, 192, 0, stream>>>(ei, hs, hv, pos, ori, W1, b1,
                                                    W2, b2, flag, out);
    }
}

// Round 3
// 750.873 us; speedup vs baseline: 1.1194x; 1.0019x over previous
//
#include <hip/hip_runtime.h>
#include <hip/hip_bf16.h>

#define N_NODESC 50000
#define N_EDGESC 1600000
#define SDIM 64
#define VDIM 32
#define HID 96
#define IN_DIMC 163

#define GRID_E 2500
#define TPB_E 10           // tiles per block (25000 tiles / 2500 blocks)
#define NXCD 8
#define XQ (GRID_E / NXCD) // 312
#define XR (GRID_E % NXCD) // 4

typedef float f32x4 __attribute__((ext_vector_type(4)));
typedef short s16x8 __attribute__((ext_vector_type(8)));

__device__ __forceinline__ float bf2f(__hip_bfloat16 x) { return __bfloat162float(x); }
__device__ __forceinline__ __hip_bfloat16 f2bf(float x) { return __float2bfloat16(x); }
__device__ __forceinline__ float bfbits2f(short b) {
    unsigned u = ((unsigned)(unsigned short)b) << 16;
    return __builtin_bit_cast(float, u);
}
__device__ __forceinline__ short f2bfbits(float x) {
    __hip_bfloat16 h = __float2bfloat16(x);
    return *(const short*)&h;
}

// ---------------------------------------------------------------------------
// Detect whether edge_index arrived as int64 (odd int32 words all zero) or int32.
__global__ void detect_kernel(const int* ei, int* flag) {
    if (blockIdx.x == 0 && threadIdx.x == 0) {
        int z = 1;
        for (int k = 0; k < 64; ++k) {
            if (ei[2 * k + 1] != 0) { z = 0; break; }
        }
        *flag = z;  // 1 -> int64 layout
    }
}

// ---------------------------------------------------------------------------
// Fused one-shot prep for the sorted tier:
//  - out = residual (hs | hv)
//  - counts = 0
//  - SrcRec[n][96..128) = bf16(hv[n])     (P part filled by precompute)
//  - WbT2  [192][64]  bf16: rows 0-95 = W1a^T (P), 96-191 = W1b^T (Q)
//  - W1cT  [96][32]   bf16: W1c^T (vector-block weights)
//  - W2Tb  [96][96]   bf16: W2^T
//  - flag = int64-layout detect
__global__ void fused_init(const float* __restrict__ hs, const float* __restrict__ hv,
                           float* __restrict__ out, int* __restrict__ counts,
                           const float* __restrict__ W1, const float* __restrict__ W2,
                           __hip_bfloat16* __restrict__ SrcRec,
                           __hip_bfloat16* __restrict__ WbT2,
                           __hip_bfloat16* __restrict__ W1cT,
                           __hip_bfloat16* __restrict__ W2Tb,
                           const int* __restrict__ ei, int* __restrict__ flag) {
    int i = blockIdx.x * blockDim.x + threadIdx.x;
    if (i < N_NODESC * (SDIM + VDIM))
        out[i] = (i < N_NODESC * SDIM) ? hs[i] : hv[i - N_NODESC * SDIM];
    if (i < N_NODESC) counts[i] = 0;
    if (i < N_NODESC * VDIM) {
        int n = i >> 5, f = i & 31;
        SrcRec[n * 128 + 96 + f] = f2bf(hv[i]);
    }
    if (i < 192 * 64) {
        int n = i >> 6, k = i & 63;
        float val = (n < 96) ? W1[k * HID + n] : W1[(64 + k) * HID + (n - 96)];
        WbT2[i] = f2bf(val);
    }
    if (i < 96 * 32) {
        int n = i >> 5, k = i & 31;
        W1cT[i] = f2bf(W1[(128 + k) * HID + n]);
    }
    if (i < 96 * 96) {
        int n = i / 96, k = i - (i / 96) * 96;
        W2Tb[i] = f2bf(W2[k * HID + n]);
    }
    if (i == 0) {
        int z = 1;
        for (int kk = 0; kk < 64; ++kk) if (ei[2 * kk + 1] != 0) { z = 0; break; }
        *flag = z;
    }
}

// ---------------------------------------------------------------------------
// MFMA node precompute (K=64): [P|Q] = hs_bf16 @ [W1a|W1b]; P (+b1) into
// SrcRec[n][0:96), Q into Qt[n][:]. 64 nodes/block, wave w owns N-strip w*48.
__global__ __launch_bounds__(256, 2) void node_precompute_mfma(
    const float* __restrict__ hs, const __hip_bfloat16* __restrict__ WbT2,
    const float* __restrict__ b1,
    __hip_bfloat16* __restrict__ SrcRec, __hip_bfloat16* __restrict__ Qt) {
    __shared__ __hip_bfloat16 sA[64][72];
    const int t = threadIdx.x;
    const int lane = t & 63;
    const int w = t >> 6;
    const int m16 = lane & 15;
    const int q = lane >> 4;
    const int nb = blockIdx.x * 64;

    for (int idx = t; idx < 64 * 64; idx += 256) {
        int node = idx >> 6, f = idx & 63;
        int g = nb + node;
        sA[node][f] = f2bf(g < N_NODESC ? hs[g * SDIM + f] : 0.f);
    }
    __syncthreads();

    // wave w covers output units n_out = w*48 + nt*16 + m16, nt = 0..2
    s16x8 bfr[3][2];
    float b1v[3];
    for (int nt = 0; nt < 3; ++nt) {
        int n_out = w * 48 + nt * 16 + m16;
        for (int kt = 0; kt < 2; ++kt)
            bfr[nt][kt] = *(const s16x8*)&WbT2[n_out * 64 + kt * 32 + q * 8];
        b1v[nt] = (n_out < 96) ? b1[n_out] : 0.f;
    }

    for (int ms = 0; ms < 4; ++ms) {
        s16x8 afr[2];
        for (int kt = 0; kt < 2; ++kt)
            afr[kt] = *(const s16x8*)&sA[ms * 16 + m16][kt * 32 + q * 8];
        f32x4 acc[3];
        for (int nt = 0; nt < 3; ++nt) acc[nt] = (f32x4){0.f, 0.f, 0.f, 0.f};
        for (int nt = 0; nt < 3; ++nt)
            for (int kt = 0; kt < 2; ++kt)
                acc[nt] = __builtin_amdgcn_mfma_f32_16x16x32_bf16(
                    afr[kt], bfr[nt][kt], acc[nt], 0, 0, 0);
        for (int nt = 0; nt < 3; ++nt) {
            int n_out = w * 48 + nt * 16 + m16;
            for (int r = 0; r < 4; ++r) {
                int node = nb + ms * 16 + q * 4 + r;
                if (node >= N_NODESC) continue;
                float v = acc[nt][r] + b1v[nt];
                if (n_out < 96) SrcRec[node * 128 + n_out] = f2bf(v);
                else            Qt[node * 96 + (n_out - 96)] = f2bf(v);
            }
        }
    }
}

// ---------------------------------------------------------------------------
// Counting sort by dst.
__global__ __launch_bounds__(256) void hist_kernel(
    const int* __restrict__ ei, const int* __restrict__ flag64,
    int* __restrict__ counts) {
    int e = blockIdx.x * blockDim.x + threadIdx.x;
    if (e >= N_EDGESC) return;
    int dN;
    if (*flag64) dN = (int)((const long long*)ei)[N_EDGESC + e];
    else dN = ei[N_EDGESC + e];
    atomicAdd(&counts[dN], 1);
}

__global__ __launch_bounds__(1024) void scan_kernel(
    const int* __restrict__ counts, int* __restrict__ cur) {
    __shared__ int part[1024];
    const int t = threadIdx.x;
    const int CH = (N_NODESC + 1023) / 1024;  // 49
    int lo = t * CH;
    int hi = lo + CH; if (hi > N_NODESC) hi = N_NODESC;
    int s = 0;
    for (int i = lo; i < hi; ++i) s += counts[i];
    part[t] = s;
    __syncthreads();
    for (int d = 1; d < 1024; d <<= 1) {
        int v = (t >= d) ? part[t - d] : 0;
        __syncthreads();
        part[t] += v;
        __syncthreads();
    }
    int run = (t == 0) ? 0 : part[t - 1];
    for (int i = lo; i < hi; ++i) {
        int c = counts[i];
        cur[i] = run;
        run += c;
    }
}

__global__ __launch_bounds__(256) void scatter_kernel(
    const int* __restrict__ ei, const int* __restrict__ flag64,
    int* __restrict__ cur, int2* __restrict__ edges) {
    int e = blockIdx.x * blockDim.x + threadIdx.x;
    if (e >= N_EDGESC) return;
    int sN, dN;
    if (*flag64) {
        const long long* e64 = (const long long*)ei;
        sN = (int)e64[e]; dN = (int)e64[N_EDGESC + e];
    } else { sN = ei[e]; dN = ei[N_EDGESC + e]; }
    int p = atomicAdd(&cur[dN], 1);
    edges[p] = make_int2(sN, dN);
}

// ---------------------------------------------------------------------------
// Main edge kernel (dst-sorted, chunked tiles, wave-local phasing).
// Per tile: each wave owns 16 edges end-to-end (geo, vrot, base, layer-1 MFMA
// + silu, layer-2 MFMA); only 2 barriers per tile (loop-top, pre-reduction).
__global__ __launch_bounds__(256, 3) void edge_kernel_sorted(
    const int2* __restrict__ edges,
    const float* __restrict__ pos, const float* __restrict__ ori,
    const float* __restrict__ W1, const __hip_bfloat16* __restrict__ W2Tb,
    const float* __restrict__ b2,
    const __hip_bfloat16* __restrict__ SrcRec, const __hip_bfloat16* __restrict__ Qt,
    const __hip_bfloat16* __restrict__ W1cT,
    float* __restrict__ out) {
    __shared__ int s_src[64], s_dst[64];
    __shared__ float s_c[64], s_s[64], s_d[64], s_cg[64], s_sg[64];
    __shared__ float s_w1d[3][HID];
    __shared__ float s_bf[64][100];           // base pre-act; reused as msg f32
    __shared__ __hip_bfloat16 hV[64][40];     // rotated hv tile (32 used)
    __shared__ __hip_bfloat16 hA[64][104];    // silu(layer1) tile
    __shared__ int s_segstart[66];

    const int t = threadIdx.x;
    const int lane = t & 63;
    const int w = t >> 6;        // wave id 0..3
    const int m16 = lane & 15;
    const int q = lane >> 4;

    // Stage geo weight rows 160..162 (once; visible after first loop barrier)
    for (int idx = t; idx < 3 * HID; idx += 256) {
        int r = idx / HID, j = idx - r * HID;
        s_w1d[r][j] = W1[(160 + r) * HID + j];
    }

    // Hoisted B fragments: W2 (18 frags) and W1c (6 frags, K=32).
    s16x8 bfr[6][3], bfrC[6];
    for (int nt = 0; nt < 6; ++nt) {
        for (int kt = 0; kt < 3; ++kt)
            bfr[nt][kt] = *(const s16x8*)&W2Tb[(nt * 16 + m16) * 96 + kt * 32 + q * 8];
        bfrC[nt] = *(const s16x8*)&W1cT[(nt * 16 + m16) * 32 + q * 8];
    }
    float b2v[6];
    for (int nt = 0; nt < 6; ++nt) b2v[nt] = b2[nt * 16 + m16];

    // Chunked, XCD-swizzled tile range: block -> chunk c -> tiles [c*TPB_E, ...)
    int b = blockIdx.x;
    int xcd = b & 7, bi = b >> 3;
    int c = (xcd < XR) ? (xcd * (XQ + 1) + bi)
                       : (XR * (XQ + 1) + (xcd - XR) * XQ + bi);
    const int tile0 = c * TPB_E;

    for (int tl = 0; tl < TPB_E; ++tl) {
        const int tile = tile0 + tl;
        __syncthreads();  // prior tile's reduction done; LDS reusable

        // --- wave-local staging: this wave's 16 edges ---
        if (lane < 16) {
            int el = w * 16 + lane;
            int2 ed = edges[tile * 64 + el];
            int sN = ed.x, dN = ed.y;
            s_src[el] = sN; s_dst[el] = dN;
            float ca, sa, cb, sb;
            __sincosf(2.0f * ori[dN], &sa, &ca);
            __sincosf(2.0f * ori[sN], &sb, &cb);
            s_c[el] = cb * ca + sb * sa;   // cos(2(beta-alpha))
            s_s[el] = sb * ca - cb * sa;   // sin(2(beta-alpha))
            float dx = pos[2 * sN] - pos[2 * dN];
            float dy = pos[2 * sN + 1] - pos[2 * dN + 1];
            float d2 = dx * dx + dy * dy;
            s_d[el] = sqrtf(d2) + 1e-6f;
            float c2f, s2f;
            if (d2 > 0.f) {
                float inv = 1.0f / d2;
                c2f = (dx * dx - dy * dy) * inv;
                s2f = 2.0f * dx * dy * inv;
            } else { c2f = 1.0f; s2f = 0.0f; }
            s_cg[el] = c2f * ca + s2f * sa;
            s_sg[el] = s2f * ca - c2f * sa;
        }

        // --- vrot staging: lane -> (edge, 4 pairs); 16B gather from SrcRec.hv ---
        {
            int el = w * 16 + (lane >> 2);
            int pp = lane & 3;
            int sN = s_src[el];                         // same-wave LDS dep
            float ce = s_c[el], se = s_s[el];
            s16x8 hvv = *(const s16x8*)&SrcRec[sN * 128 + 96 + pp * 8];
            s16x8 rv;
            for (int p2 = 0; p2 < 4; ++p2) {
                float x = bfbits2f(hvv[2 * p2]), y = bfbits2f(hvv[2 * p2 + 1]);
                rv[2 * p2]     = f2bfbits(ce * x - se * y);
                rv[2 * p2 + 1] = f2bfbits(se * x + ce * y);
            }
            *(s16x8*)&hV[el][pp * 8] = rv;
        }

        // --- base staging: P[src] + Q[dst] + geo terms -> s_bf (f32) ---
        for (int i2 = 0; i2 < 3; ++i2) {
            int idx = i2 * 64 + lane;          // 0..191 over (16 edges x 12 jb)
            int el = w * 16 + idx / 12;
            int j = (idx - (idx / 12) * 12) * 8;
            int sN = s_src[el], dN = s_dst[el];
            s16x8 Pv = *(const s16x8*)&SrcRec[sN * 128 + j];
            s16x8 Qv = *(const s16x8*)&Qt[dN * 96 + j];
            float de = s_d[el], cge = s_cg[el], sge = s_sg[el];
            f32x4 o0, o1;
            for (int k2 = 0; k2 < 4; ++k2) {
                o0[k2] = bfbits2f(Pv[k2]) + bfbits2f(Qv[k2])
                       + de * s_w1d[0][j + k2] + cge * s_w1d[1][j + k2]
                       + sge * s_w1d[2][j + k2];
                o1[k2] = bfbits2f(Pv[4 + k2]) + bfbits2f(Qv[4 + k2])
                       + de * s_w1d[0][j + 4 + k2] + cge * s_w1d[1][j + 4 + k2]
                       + sge * s_w1d[2][j + 4 + k2];
            }
            *(f32x4*)&s_bf[el][j] = o0;
            *(f32x4*)&s_bf[el][j + 4] = o1;
        }

        // --- layer-1 vector part via MFMA (K=32), + base, silu -> hA ---
        {
            s16x8 afrV = *(const s16x8*)&hV[w * 16 + m16][q * 8];
            f32x4 acc1[6];
            for (int nt = 0; nt < 6; ++nt)
                acc1[nt] = __builtin_amdgcn_mfma_f32_16x16x32_bf16(
                    afrV, bfrC[nt], (f32x4){0.f, 0.f, 0.f, 0.f}, 0, 0, 0);
            for (int nt = 0; nt < 6; ++nt) {
                int u = nt * 16 + m16;
                for (int r = 0; r < 4; ++r) {
                    int el = w * 16 + q * 4 + r;
                    float pre = acc1[nt][r] + s_bf[el][u];
                    float h = pre / (1.0f + __expf(-pre));
                    hA[el][u] = f2bf(h);
                }
            }
        }

        // --- layer 2 via MFMA; msg (f32) overwrites s_bf (wave-private rows) ---
        {
            s16x8 afr[3];
            for (int kt = 0; kt < 3; ++kt)
                afr[kt] = *(const s16x8*)&hA[w * 16 + m16][kt * 32 + q * 8];
            f32x4 acc[6];
            for (int nt = 0; nt < 6; ++nt) acc[nt] = (f32x4){0.f, 0.f, 0.f, 0.f};
            for (int nt = 0; nt < 6; ++nt)
                for (int kt = 0; kt < 3; ++kt)
                    acc[nt] = __builtin_amdgcn_mfma_f32_16x16x32_bf16(
                        afr[kt], bfr[nt][kt], acc[nt], 0, 0, 0);
            for (int nt = 0; nt < 6; ++nt) {
                int u = nt * 16 + m16;
                float bb = b2v[nt];
                for (int r = 0; r < 4; ++r) {
                    int el = w * 16 + q * 4 + r;
                    s_bf[el][u] = acc[nt][r] + bb;
                }
            }
        }
        __syncthreads();  // all waves' msg + s_dst complete

        // --- segments: recomputed redundantly per wave (identical writes) ---
        int dl = s_dst[lane];
        int dp = (lane > 0) ? s_dst[lane - 1] : -1;
        bool bnd = (lane > 0) && (dl != dp);
        unsigned long long mask = __ballot(bnd);
        int nseg = (int)__popcll(mask) + 1;
        if (bnd) s_segstart[__popcll(mask & (~0ull >> (63 - lane)))] = lane;
        if (lane == 0) s_segstart[0] = 0;

        // --- reduction: one atomicAdd per (segment, unit) ---
        for (int idx = t; idx < nseg * HID; idx += 256) {
            int sg = idx / HID;
            int u = idx - sg * HID;
            int e0 = s_segstart[sg];
            int e1 = (sg + 1 < nseg) ? s_segstart[sg + 1] : 64;
            float sum = 0.f;
            for (int e = e0; e < e1; ++e) sum += s_bf[e][u];
            int dN = s_dst[e0];
            if (u < SDIM) atomicAdd(&out[dN * SDIM + u], sum);
            else atomicAdd(&out[N_NODESC * SDIM + dN * VDIM + (u - SDIM)], sum);
        }
    }
}

// ---------------------------------------------------------------------------
// Mid-tier: f32 per-node precompute (4 tables) + unsorted atomic-scatter kernel.
__global__ __launch_bounds__(128) void node_precompute(
    const float* __restrict__ hs, const float* __restrict__ hv,
    const float* __restrict__ W1, const float* __restrict__ b1,
    __hip_bfloat16* __restrict__ Pp, __hip_bfloat16* __restrict__ Qt,
    __hip_bfloat16* __restrict__ Ut, __hip_bfloat16* __restrict__ Vt) {
    int n = blockIdx.x;
    __shared__ float s_hs[SDIM];
    __shared__ float s_hv[VDIM];
    int t = threadIdx.x;
    if (t < 64) s_hs[t] = hs[n * SDIM + t];
    else if (t < 96) s_hv[t - 64] = hv[n * VDIM + (t - 64)];
    __syncthreads();
    if (t < HID) {
        float p = b1[t], qq = 0.f, u = 0.f, v = 0.f;
        for (int k = 0; k < 64; ++k) {
            float x = s_hs[k];
            p += x * W1[k * HID + t];
            qq += x * W1[(64 + k) * HID + t];
        }
        for (int pr = 0; pr < 16; ++pr) {
            float x = s_hv[2 * pr], y = s_hv[2 * pr + 1];
            float wa = W1[(128 + 2 * pr) * HID + t];
            float wb = W1[(128 + 2 * pr + 1) * HID + t];
            u += x * wa + y * wb;
            v += x * wb - y * wa;
        }
        Pp[n * HID + t] = f2bf(p);
        Qt[n * HID + t] = f2bf(qq);
        Ut[n * HID + t] = f2bf(u);
        Vt[n * HID + t] = f2bf(v);
    }
}

__global__ void init_out(const float* __restrict__ hs, const float* __restrict__ hv,
                         float* __restrict__ out) {
    int i = blockIdx.x * blockDim.x + threadIdx.x;
    if (i >= N_NODESC * (SDIM + VDIM)) return;
    out[i] = (i < N_NODESC * SDIM) ? hs[i] : hv[i - N_NODESC * SDIM];
}

__global__ __launch_bounds__(256) void edge_kernel(
    const int* __restrict__ ei, const float* __restrict__ pos,
    const float* __restrict__ ori, const float* __restrict__ W1,
    const float* __restrict__ W2, const float* __restrict__ b2,
    const __hip_bfloat16* __restrict__ Pp, const __hip_bfloat16* __restrict__ Qt,
    const __hip_bfloat16* __restrict__ Ut, const __hip_bfloat16* __restrict__ Vt,
    const int* __restrict__ flag64, float* __restrict__ out) {
    __shared__ int s_src[64], s_dst[64];
    __shared__ float s_c[64], s_s[64], s_d[64], s_cg[64], s_sg[64];
    __shared__ float s_w1d[3][HID];
    __shared__ __hip_bfloat16 hA[64][104];
    __shared__ __hip_bfloat16 W2T[HID][104];

    const int t = threadIdx.x;
    const int lane = t & 63;
    const int w = t >> 6;
    const int m16 = lane & 15;
    const int q = lane >> 4;

    for (int idx = t; idx < HID * HID; idx += 256) {
        int k = idx / HID;
        int n = idx - k * HID;
        W2T[n][k] = f2bf(W2[idx]);
    }
    for (int idx = t; idx < 3 * HID; idx += 256) {
        int r = idx / HID, j = idx - r * HID;
        s_w1d[r][j] = W1[(160 + r) * HID + j];
    }
    __syncthreads();

    s16x8 bfr[6][3];
    for (int nt = 0; nt < 6; ++nt)
        for (int kt = 0; kt < 3; ++kt)
            bfr[nt][kt] = *(const s16x8*)&W2T[nt * 16 + m16][kt * 32 + q * 8];
    float b2v[6];
    for (int nt = 0; nt < 6; ++nt) b2v[nt] = b2[nt * 16 + m16];

    const bool i64 = (*flag64 != 0);
    const long long* ei64 = (const long long*)ei;

    for (int tile = blockIdx.x; tile < N_EDGESC / 64; tile += gridDim.x) {
        __syncthreads();

        if (t < 64) {
            int e = tile * 64 + t;
            int sN, dN;
            if (i64) { sN = (int)ei64[e]; dN = (int)ei64[N_EDGESC + e]; }
            else     { sN = ei[e];        dN = ei[N_EDGESC + e]; }
            s_src[t] = sN; s_dst[t] = dN;
            float ca, sa, cb, sb;
            __sincosf(2.0f * ori[dN], &sa, &ca);
            __sincosf(2.0f * ori[sN], &sb, &cb);
            s_c[t] = cb * ca + sb * sa;
            s_s[t] = sb * ca - cb * sa;
            float dx = pos[2 * sN] - pos[2 * dN];
            float dy = pos[2 * sN + 1] - pos[2 * dN + 1];
            float d2 = dx * dx + dy * dy;
            s_d[t] = sqrtf(d2) + 1e-6f;
            float c2f, s2f;
            if (d2 > 0.f) {
                float inv = 1.0f / d2;
                c2f = (dx * dx - dy * dy) * inv;
                s2f = 2.0f * dx * dy * inv;
            } else { c2f = 1.0f; s2f = 0.0f; }
            s_cg[t] = c2f * ca + s2f * sa;
            s_sg[t] = s2f * ca - c2f * sa;
        }
        __syncthreads();

        for (int p = 0; p < 24; ++p) {
            int idx = p * 256 + t;
            int e = idx / HID;
            int j = idx - e * HID;
            int sN = s_src[e], dN = s_dst[e];
            float pre = bf2f(Pp[sN * HID + j]) + bf2f(Qt[dN * HID + j])
                      + s_c[e] * bf2f(Ut[sN * HID + j])
                      + s_s[e] * bf2f(Vt[sN * HID + j])
                      + s_d[e] * s_w1d[0][j] + s_cg[e] * s_w1d[1][j]
                      + s_sg[e] * s_w1d[2][j];
            float h = pre / (1.0f + __expf(-pre));
            hA[e][j] = f2bf(h);
        }
        __syncthreads();

        f32x4 acc[6];
        for (int nt = 0; nt < 6; ++nt) acc[nt] = (f32x4){0.f, 0.f, 0.f, 0.f};
        s16x8 afr[3];
        for (int kt = 0; kt < 3; ++kt)
            afr[kt] = *(const s16x8*)&hA[w * 16 + m16][kt * 32 + q * 8];
        for (int nt = 0; nt < 6; ++nt)
            for (int kt = 0; kt < 3; ++kt)
                acc[nt] = __builtin_amdgcn_mfma_f32_16x16x32_bf16(
                    afr[kt], bfr[nt][kt], acc[nt], 0, 0, 0);

        for (int nt = 0; nt < 6; ++nt) {
            int u = nt * 16 + m16;
            for (int r = 0; r < 4; ++r) {
                int eloc = w * 16 + q * 4 + r;
                int dN = s_dst[eloc];
                float val = acc[nt][r] + b2v[nt];
                if (u < SDIM) atomicAdd(&out[dN * SDIM + u], val);
                else atomicAdd(&out[N_NODESC * SDIM + dN * VDIM + (u - SDIM)], val);
            }
        }
    }
}

// ---------------------------------------------------------------------------
// Fallback (ws too small for tables): fully per-edge, correct but slow.
__global__ __launch_bounds__(192) void edge_fallback(
    const int* __restrict__ ei, const float* __restrict__ hs,
    const float* __restrict__ hv, const float* __restrict__ pos,
    const float* __restrict__ ori, const float* __restrict__ W1,
    const float* __restrict__ b1, const float* __restrict__ W2,
    const float* __restrict__ b2, const int* __restrict__ flag64,
    float* __restrict__ out) {
    __shared__ float s_msg[IN_DIMC];
    __shared__ float s_h[HID];
    int e = blockIdx.x;
    int t = threadIdx.x;
    const bool i64 = (*flag64 != 0);
    int sN, dN;
    if (i64) {
        const long long* e64 = (const long long*)ei;
        sN = (int)e64[e]; dN = (int)e64[N_EDGESC + e];
    } else { sN = ei[e]; dN = ei[N_EDGESC + e]; }

    if (t < IN_DIMC) {
        if (t < 64) s_msg[t] = hs[sN * SDIM + t];
        else if (t < 128) s_msg[t] = hs[dN * SDIM + (t - 64)];
        else {
            float ca, sa, cb, sb;
            __sincosf(2.0f * ori[dN], &sa, &ca);
            __sincosf(2.0f * ori[sN], &sb, &cb);
            float c = cb * ca + sb * sa;
            float s = sb * ca - cb * sa;
            float dx = pos[2 * sN] - pos[2 * dN];
            float dy = pos[2 * sN + 1] - pos[2 * dN + 1];
            float d2 = dx * dx + dy * dy;
            if (t < 160) {
                int pr = (t - 128) >> 1;
                float x = hv[sN * VDIM + 2 * pr], y = hv[sN * VDIM + 2 * pr + 1];
                s_msg[t] = ((t & 1) == 0) ? (c * x - s * y) : (s * x + c * y);
            } else if (t == 160) s_msg[t] = sqrtf(d2) + 1e-6f;
            else {
                float c2f = 1.0f, s2f = 0.0f;
                if (d2 > 0.f) {
                    float inv = 1.0f / d2;
                    c2f = (dx * dx - dy * dy) * inv;
                    s2f = 2.0f * dx * dy * inv;
                }
                s_msg[t] = (t == 161) ? (c2f * ca + s2f * sa) : (s2f * ca - c2f * sa);
            }
        }
    }
    __syncthreads();
    if (t < HID) {
        float a = b1[t];
        for (int k = 0; k < IN_DIMC; ++k) a += s_msg[k] * W1[k * HID + t];
        s_h[t] = a / (1.0f + __expf(-a));
    }
    __syncthreads();
    if (t < HID) {
        float a = b2[t];
        for (int k = 0; k < HID; ++k) a += s_h[k] * W2[k * HID + t];
        if (t < SDIM) atomicAdd(&out[dN * SDIM + t], a);
        else atomicAdd(&out[N_NODESC * SDIM + dN * VDIM + (t - SDIM)], a);
    }
}

// ---------------------------------------------------------------------------
extern "C" void kernel_launch(void* const* d_in, const int* in_sizes, int n_in,
                              void* d_out, int out_size, void* d_ws, size_t ws_size,
                              hipStream_t stream) {
    const float* hs  = (const float*)d_in[0];
    const float* hv  = (const float*)d_in[1];
    const int*   ei  = (const int*)d_in[2];
    const float* pos = (const float*)d_in[3];
    const float* ori = (const float*)d_in[4];
    const float* W1  = (const float*)d_in[5];
    const float* b1  = (const float*)d_in[6];
    const float* W2  = (const float*)d_in[7];
    const float* b2  = (const float*)d_in[8];
    float* out = (float*)d_out;

    // sorted-tier workspace layout (256B-aligned chunks)
    const size_t SREC = (size_t)N_NODESC * 128 * sizeof(__hip_bfloat16);  // 12.8 MB
    const size_t QTB  = (size_t)N_NODESC * 96 * sizeof(__hip_bfloat16);   // 9.6 MB
    const size_t CNT  = ((size_t)N_NODESC * sizeof(int) + 255) & ~255ull; // 200 KB
    const size_t EDG  = (size_t)N_EDGESC * sizeof(int2);                  // 12.8 MB
    const size_t WBT2 = ((size_t)192 * 64 * 2 + 255) & ~255ull;
    const size_t W1CT = ((size_t)96 * 32 * 2 + 255) & ~255ull;
    const size_t W2TS = ((size_t)96 * 96 * 2 + 255) & ~255ull;
    const size_t SORT_WS = SREC + QTB + 2 * CNT + EDG + WBT2 + W1CT + W2TS + 256;

    const size_t TBL = (size_t)N_NODESC * HID * sizeof(__hip_bfloat16);   // 9.6 MB
    const bool big = ws_size >= 4 * TBL + 16;
    const bool srt = ws_size >= SORT_WS;

    if (srt) {
        char* ws = (char*)d_ws;
        __hip_bfloat16* SrcRec = (__hip_bfloat16*)(ws);
        __hip_bfloat16* Qt     = (__hip_bfloat16*)(ws + SREC);
        int* counts            = (int*)(ws + SREC + QTB);
        int* cur               = (int*)(ws + SREC + QTB + CNT);
        int2* edges            = (int2*)(ws + SREC + QTB + 2 * CNT);
        __hip_bfloat16* WbT2   = (__hip_bfloat16*)(ws + SREC + QTB + 2 * CNT + EDG);
        __hip_bfloat16* W1cT   = (__hip_bfloat16*)(ws + SREC + QTB + 2 * CNT + EDG + WBT2);
        __hip_bfloat16* W2Tb   = (__hip_bfloat16*)(ws + SREC + QTB + 2 * CNT + EDG + WBT2 + W1CT);
        int* flag              = (int*)(ws + SREC + QTB + 2 * CNT + EDG + WBT2 + W1CT + W2TS);

        fused_init<<<(N_NODESC * (SDIM + VDIM) + 255) / 256, 256, 0, stream>>>(
            hs, hv, out, counts, W1, W2, SrcRec, WbT2, W1cT, W2Tb, ei, flag);
        hist_kernel<<<N_EDGESC / 256, 256, 0, stream>>>(ei, flag, counts);
        scan_kernel<<<1, 1024, 0, stream>>>(counts, cur);
        scatter_kernel<<<N_EDGESC / 256, 256, 0, stream>>>(ei, flag, cur, edges);
        node_precompute_mfma<<<(N_NODESC + 63) / 64, 256, 0, stream>>>(
            hs, WbT2, b1, SrcRec, Qt);
        edge_kernel_sorted<<<GRID_E, 256, 0, stream>>>(edges, pos, ori, W1, W2Tb, b2,
                                                       SrcRec, Qt, W1cT, out);
    } else if (big) {
        char* ws = (char*)d_ws;
        __hip_bfloat16* Pp = (__hip_bfloat16*)(ws);
        __hip_bfloat16* Qt = (__hip_bfloat16*)(ws + TBL);
        __hip_bfloat16* Ut = (__hip_bfloat16*)(ws + 2 * TBL);
        __hip_bfloat16* Vt = (__hip_bfloat16*)(ws + 3 * TBL);
        int* flag = (int*)(ws + 4 * TBL);
        init_out<<<(N_NODESC * (SDIM + VDIM) + 255) / 256, 256, 0, stream>>>(hs, hv, out);
        detect_kernel<<<1, 64, 0, stream>>>(ei, flag);
        node_precompute<<<N_NODESC, 128, 0, stream>>>(hs, hv, W1, b1, Pp, Qt, Ut, Vt);
        edge_kernel<<<2500, 256, 0, stream>>>(ei, pos, ori, W1, W2, b2,
                                              Pp, Qt, Ut, Vt, flag, out);
    } else {
        int* flag = (int*)d_ws;
        init_out<<<(N_NODESC * (SDIM + VDIM) + 255) / 256, 256, 0, stream>>>(hs, hv, out);
        detect_kernel<<<1, 64, 0, stream>>>(ei, flag);
        edge_fallback<<<N_EDGESC, 192, 0, stream>>>(ei, hs, hv, pos, ori, W1, b1,
                                                    W2, b2, flag, out);
    }
}